// Round 9
// baseline (381.636 us; speedup 1.0000x reference)
//
#include <hip/hip_runtime.h>
#include <hip/hip_bf16.h>

#define B_N 64
#define S_N 2048
#define E_N 512
#define A_N 512
#define SPN (B_N * S_N)   // 131072 rows

typedef __bf16 bf16x8 __attribute__((ext_vector_type(8)));
typedef float  f32x4  __attribute__((ext_vector_type(4)));

__device__ __forceinline__ unsigned int f2bfu(float f) {
  return (unsigned int)__builtin_bit_cast(unsigned short, (__bf16)f);
}

// ------- K0a: pack W_enc fp32 [A][E] -> bf16 in MFMA-fragment order --------
// chunk pk = (c*16 + k32)*64 + l (16 B each), l = q*16+ln
// holds W[a = c*16+ln][k = k32*32 + q*8 + j], j=0..7
__global__ __launch_bounds__(256) void k_pack(const float* __restrict__ W,
                                              unsigned short* __restrict__ Wp) {
  const int pk = blockIdx.x * 256 + threadIdx.x;      // [0, 32768)
  const int l = pk & 63, k32 = (pk >> 6) & 15, c = pk >> 10;
  const int ln = l & 15, q = l >> 4;
  const int a = c * 16 + ln, k = k32 * 32 + q * 8;
  const float* src = W + (size_t)a * E_N + k;
  const float4 u = *(const float4*)src;
  const float4 w = *(const float4*)(src + 4);
  uint4 o;
  o.x = f2bfu(u.x) | (f2bfu(u.y) << 16);
  o.y = f2bfu(u.z) | (f2bfu(u.w) << 16);
  o.z = f2bfu(w.x) | (f2bfu(w.y) << 16);
  o.w = f2bfu(w.z) | (f2bfu(w.w) << 16);
  *(uint4*)(Wp + (size_t)pk * 8) = o;
}

// ------- K0b: dec_proj[b][a] = dot(dec_hidden[b], W_dec[a]) ----------------
__global__ __launch_bounds__(256) void k_decproj(const float* __restrict__ dh,
                                                 const float* __restrict__ Wd,
                                                 float* __restrict__ decp) {
  const int b = blockIdx.x, tid = threadIdx.x;
  __shared__ float h[E_N];
  h[tid] = dh[b * E_N + tid];
  h[tid + 256] = dh[b * E_N + 256 + tid];
  __syncthreads();
  for (int a = tid; a < A_N; a += 256) {
    const float* wr = Wd + (size_t)a * E_N;
    float s = 0.f;
    #pragma unroll 8
    for (int e = 0; e < E_N; e += 4) {
      const float4 w4 = *(const float4*)(wr + e);
      s += w4.x * h[e] + w4.y * h[e + 1] + w4.z * h[e + 2] + w4.w * h[e + 3];
    }
    decp[b * A_N + a] = s;
  }
}

// ------- K1: W-STATIONARY persistent partial-scores kernel ------------------
// grid=256 (1/CU). bid -> xcd=bid&7, slot=bid>>3; row-group r=(slot>>3)*8+xcd
// (4096 rows), col-group c8=slot&7 (64 A-cols). The 8 col-blocks of a
// row-group share one XCD -> enc shared via its L2. W slice (64 KB) in LDS,
// loaded ONCE. 64 sub-tiles of 64 rows x full-K in LDS (R6 layout).
// 8 waves: wr=wv&1 (32 rows), wc4=wv>>1 (16 cols); acc[2] per wave.
// Output: sp[c8][row] partial scores (summed in k_softmax).
#define LDSA 65536
#define LDSW 65536
#define LDS2 (LDSA + LDSW + 1024)

__device__ __forceinline__ int a_off(int r, int kb) {
  return r * 1024 + (kb ^ ((r & 7) << 4));
}

__global__ __launch_bounds__(512, 2) void k_scores(
    const float* __restrict__ enc, const unsigned short* __restrict__ Wp,
    const float* __restrict__ decp, const float* __restrict__ vvec,
    float* __restrict__ sp) {
  __shared__ __align__(16) unsigned char lds[LDS2];
  const int tid = threadIdx.x;
  const int lane = tid & 63, wv = tid >> 6, q = lane >> 4, ln = lane & 15;
  const int wr = wv & 1, wc4 = wv >> 1;
  const int bid = blockIdx.x;
  const int xcd = bid & 7, slot = bid >> 3;
  const int rg = (slot >> 3) * 8 + xcd;          // row-group 0..31
  const int c8 = slot & 7;                        // col-group 0..7
  const size_t rowbase = (size_t)rg * 4096;
  const int b0 = rg * 2;

  // per-thread epilogue constants (this wave's single col)
  const int col = c8 * 64 + wc4 * 16 + ln;
  const float vvv  = vvec[col];
  const float dpv0 = decp[b0 * A_N + col];
  const float dpv1 = decp[(b0 + 1) * A_N + col];

  // ---- load W slice (64 KB, contiguous chunk range of Wp) into LDS ----
  {
    const uint4* wsrc = (const uint4*)(Wp + (size_t)c8 * 4096 * 8);
    uint4* wdst = (uint4*)(lds + LDSA);
    #pragma unroll
    for (int i = 0; i < 8; ++i) wdst[i * 512 + tid] = wsrc[i * 512 + tid];
  }
  // ---- stage A[0]: wave stages rows rowbase+wv*8..+8, full 2KB/row ----
  {
    const float* srow = enc + (rowbase + (size_t)wv * 8) * E_N + lane * 8;
    #pragma unroll 2
    for (int r8 = 0; r8 < 8; ++r8) {
      const f32x4 u = *(const f32x4*)(srow + (size_t)r8 * E_N);
      const f32x4 w = *(const f32x4*)(srow + (size_t)r8 * E_N + 4);
      uint4 o;
      o.x = f2bfu(u.x) | (f2bfu(u.y) << 16);
      o.y = f2bfu(u.z) | (f2bfu(u.w) << 16);
      o.z = f2bfu(w.x) | (f2bfu(w.y) << 16);
      o.w = f2bfu(w.z) | (f2bfu(w.w) << 16);
      *(uint4*)(lds + a_off(wv * 8 + r8, lane * 16)) = o;
    }
  }
  __syncthreads();

  float* red = (float*)(lds + LDSA + LDSW);
  const unsigned char* ldsw = lds + LDSA;

  for (int j = 0; j < 64; ++j) {
    // issue next sub-tile's loads early (write-late after barrier)
    f32x4 L[16];
    if (j < 63) {
      const float* nb =
          enc + (rowbase + (size_t)(j + 1) * 64 + wv * 8) * E_N + lane * 8;
      #pragma unroll
      for (int rr = 0; rr < 8; ++rr) {
        L[rr * 2]     = *(const f32x4*)(nb + (size_t)rr * E_N);
        L[rr * 2 + 1] = *(const f32x4*)(nb + (size_t)rr * E_N + 4);
      }
    }
    // ---- compute: rolled 16 K-steps; B from LDS W, A from LDS ----
    f32x4 acc[2] = {};
    #pragma unroll 1
    for (int kss = 0; kss < 16; ++kss) {
      const bf16x8 bfr =
          *(const bf16x8*)(ldsw + ((wc4 * 16 + kss) * 64 + lane) * 16);
      const bf16x8 a0 =
          *(const bf16x8*)(lds + a_off(wr * 32 + ln, kss * 64 + q * 16));
      const bf16x8 a1 =
          *(const bf16x8*)(lds + a_off(wr * 32 + 16 + ln, kss * 64 + q * 16));
      acc[0] = __builtin_amdgcn_mfma_f32_16x16x32_bf16(a0, bfr, acc[0], 0, 0, 0);
      acc[1] = __builtin_amdgcn_mfma_f32_16x16x32_bf16(a1, bfr, acc[1], 0, 0, 0);
    }
    // ---- epilogue (registers): tanh(x+dp)*v, reduce over this wave's 16 cols
    const float dpv = (j < 32) ? dpv0 : dpv1;
    #pragma unroll
    for (int mt = 0; mt < 2; ++mt) {
      #pragma unroll
      for (int rr = 0; rr < 4; ++rr) {
        float x = acc[mt][rr] + dpv;
        x = fminf(9.f, fmaxf(-9.f, x));
        const float ex = __expf(2.f * x);
        float s = __fdividef(ex - 1.f, ex + 1.f) * vvv;
        s += __shfl_xor(s, 1);
        s += __shfl_xor(s, 2);
        s += __shfl_xor(s, 4);
        s += __shfl_xor(s, 8);
        if (ln == 0) red[wv * 32 + mt * 16 + q * 4 + rr] = s;
      }
    }
    __syncthreads();   // compute reads of A[j] done; red written
    // write A[j+1] (reg->LDS), overwriting A[j]
    if (j < 63) {
      #pragma unroll
      for (int rr = 0; rr < 8; ++rr) {
        uint4 o;
        o.x = f2bfu(L[rr * 2].x)     | (f2bfu(L[rr * 2].y)     << 16);
        o.y = f2bfu(L[rr * 2].z)     | (f2bfu(L[rr * 2].w)     << 16);
        o.z = f2bfu(L[rr * 2 + 1].x) | (f2bfu(L[rr * 2 + 1].y) << 16);
        o.w = f2bfu(L[rr * 2 + 1].z) | (f2bfu(L[rr * 2 + 1].w) << 16);
        *(uint4*)(lds + a_off(wv * 8 + rr, lane * 16)) = o;
      }
    }
    // combine the 4 col-16-group waves of each row half; write partials
    if (tid < 64) {
      const int wr_ = tid >> 5, l32 = tid & 31;
      const float s = red[(0 * 2 + wr_) * 32 + l32] +
                      red[(1 * 2 + wr_) * 32 + l32] +
                      red[(2 * 2 + wr_) * 32 + l32] +
                      red[(3 * 2 + wr_) * 32 + l32];
      sp[(size_t)c8 * SPN + rowbase + (size_t)j * 64 + tid] = s;
    }
    __syncthreads();   // A[j+1] ready; red consumed
  }
}

// ------- K2: softmax over S per b (sums the 8 col-group partials) -----------
__global__ __launch_bounds__(256) void k_softmax(const float* __restrict__ sp,
                                                 float* __restrict__ attn) {
  const int b = blockIdx.x, tid = threadIdx.x;
  float l[8];
  float mx = -3.4e38f;
  #pragma unroll
  for (int i = 0; i < 8; ++i) {
    const size_t idx = (size_t)b * S_N + i * 256 + tid;
    float s = 0.f;
    #pragma unroll
    for (int c = 0; c < 8; ++c) s += sp[(size_t)c * SPN + idx];
    l[i] = s;
    mx = fmaxf(mx, l[i]);
  }
  #pragma unroll
  for (int m = 1; m < 64; m <<= 1) mx = fmaxf(mx, __shfl_xor(mx, m));
  __shared__ float sred[8];
  if ((tid & 63) == 0) sred[tid >> 6] = mx;
  __syncthreads();
  mx = fmaxf(fmaxf(sred[0], sred[1]), fmaxf(sred[2], sred[3]));
  float se = 0.f;
  #pragma unroll
  for (int i = 0; i < 8; ++i) { l[i] = __expf(l[i] - mx); se += l[i]; }
  #pragma unroll
  for (int m = 1; m < 64; m <<= 1) se += __shfl_xor(se, m);
  if ((tid & 63) == 0) sred[4 + (tid >> 6)] = se;
  __syncthreads();
  se = sred[4] + sred[5] + sred[6] + sred[7];
  const float inv = 1.f / se;
  #pragma unroll
  for (int i = 0; i < 8; ++i) attn[b * S_N + i * 256 + tid] = l[i] * inv;
}

// ------- K3: context[b][e] = sum_s w[b][s] * enc[b][s][e] -------------------
__global__ __launch_bounds__(512) void k_context(const float* __restrict__ enc,
                                                 const float* __restrict__ attn,
                                                 float* __restrict__ ctx) {
  const int blk = blockIdx.x;
  const int b = blk >> 2, eq = blk & 3;
  const int tid = threadIdx.x;
  const int te = tid & 31, sg = tid >> 5;   // 16 s-groups of 128 rows
  const int e0 = eq * 128 + te * 4;
  const float* ep = enc + (size_t)b * S_N * E_N + e0;
  const float* wp = attn + b * S_N;
  f32x4 acc = {0.f, 0.f, 0.f, 0.f};
  const int s0 = sg * 128;
  #pragma unroll 4
  for (int s = s0; s < s0 + 128; ++s) {
    const float w = wp[s];
    const f32x4 ev = *(const f32x4*)(ep + (size_t)s * E_N);
    acc += w * ev;
  }
  __shared__ f32x4 red[16][32];
  red[sg][te] = acc;
  __syncthreads();
  if (sg == 0) {
    f32x4 t = red[0][te];
    #pragma unroll
    for (int g = 1; g < 16; ++g) t += red[g][te];
    *(f32x4*)(ctx + (size_t)b * E_N + e0) = t;
  }
}

// ------- launch -------------------------------------------------------------
extern "C" void kernel_launch(void* const* d_in, const int* in_sizes, int n_in,
                              void* d_out, int out_size, void* d_ws, size_t ws_size,
                              hipStream_t stream) {
  const float* enc = (const float*)d_in[0];
  const float* dh  = (const float*)d_in[1];
  const float* We  = (const float*)d_in[2];
  const float* Wd  = (const float*)d_in[3];
  const float* v   = (const float*)d_in[4];

  float* out_ctx  = (float*)d_out;
  float* out_attn = out_ctx + B_N * E_N;

  float* sp   = (float*)d_ws;                         // 8 x 131072 f32 partials
  float* decp = sp + 8 * SPN;                         // 32768 f32
  unsigned short* Wp = (unsigned short*)(decp + B_N * A_N);  // 262144 bf16 packed

  k_pack   <<<128, 256, 0, stream>>>(We, Wp);
  k_decproj<<<B_N, 256, 0, stream>>>(dh, Wd, decp);
  k_scores <<<256, 512, 0, stream>>>(enc, Wp, decp, v, sp);
  k_softmax<<<B_N, 256, 0, stream>>>(sp, out_attn);
  k_context<<<B_N * 4, 512, 0, stream>>>(enc, out_attn, out_ctx);
}

// Round 10
// 211.076 us; speedup vs baseline: 1.8080x; 1.8080x over previous
//
#include <hip/hip_runtime.h>
#include <hip/hip_bf16.h>

#define B_N 64
#define S_N 2048
#define E_N 512
#define A_N 512

typedef __bf16 bf16x8 __attribute__((ext_vector_type(8)));
typedef float  f32x4  __attribute__((ext_vector_type(4)));

__device__ __forceinline__ unsigned int f2bfu(float f) {
  return (unsigned int)__builtin_bit_cast(unsigned short, (__bf16)f);
}

// ------- K0a: pack W_enc fp32 [A][E] -> bf16 in MFMA-fragment order --------
// chunk pk = (c*16 + k32)*64 + l (16 B each), l = q*16+ln
// holds W[a = c*16+ln][k = k32*32 + q*8 + j], j=0..7
__global__ __launch_bounds__(256) void k_pack(const float* __restrict__ W,
                                              unsigned short* __restrict__ Wp) {
  const int pk = blockIdx.x * 256 + threadIdx.x;      // [0, 32768)
  const int l = pk & 63, k32 = (pk >> 6) & 15, c = pk >> 10;
  const int ln = l & 15, q = l >> 4;
  const int a = c * 16 + ln, k = k32 * 32 + q * 8;
  const float* src = W + (size_t)a * E_N + k;
  const float4 u = *(const float4*)src;
  const float4 w = *(const float4*)(src + 4);
  uint4 o;
  o.x = f2bfu(u.x) | (f2bfu(u.y) << 16);
  o.y = f2bfu(u.z) | (f2bfu(u.w) << 16);
  o.z = f2bfu(w.x) | (f2bfu(w.y) << 16);
  o.w = f2bfu(w.z) | (f2bfu(w.w) << 16);
  *(uint4*)(Wp + (size_t)pk * 8) = o;
}

// ------- K0b: dec_proj[b][a] = dot(dec_hidden[b], W_dec[a]) ----------------
__global__ __launch_bounds__(256) void k_decproj(const float* __restrict__ dh,
                                                 const float* __restrict__ Wd,
                                                 float* __restrict__ decp) {
  const int b = blockIdx.x, tid = threadIdx.x;
  __shared__ float h[E_N];
  h[tid] = dh[b * E_N + tid];
  h[tid + 256] = dh[b * E_N + 256 + tid];
  __syncthreads();
  for (int a = tid; a < A_N; a += 256) {
    const float* wr = Wd + (size_t)a * E_N;
    float s = 0.f;
    #pragma unroll 8
    for (int e = 0; e < E_N; e += 4) {
      const float4 w4 = *(const float4*)(wr + e);
      s += w4.x * h[e] + w4.y * h[e + 1] + w4.z * h[e + 2] + w4.w * h[e + 3];
    }
    decp[b * A_N + a] = s;
  }
}

// ------- K1: scores = sum_a v[a]*tanh(enc@We^T + decp) ---------------------
// R6 structure scaled to Rw=128: block = 128 rows x 512 cols, 8 waves,
// wave = 128 rows x 64 cols, acc[8][4]. A full-K (128 rows x 1KB bf16) in
// LDS, zero K-loop barriers. W read ONCE per block (536 MB total vs R6 1GB).
#define LDS_A   131072                // 128 rows x 1024 B
#define RED_OFF LDS_A
#define LDS_TOT (LDS_A + 8 * 128 * 4)

__device__ __forceinline__ int a_off(int r, int kb) {
  return r * 1024 + (kb ^ ((r & 7) << 4));
}

__global__ __launch_bounds__(512) void k_scores(
    const float* __restrict__ enc, const unsigned short* __restrict__ Wp,
    const float* __restrict__ decp, const float* __restrict__ vvec,
    float* __restrict__ scores) {
  __shared__ __align__(16) unsigned char lds[LDS_TOT];
  const int tid = threadIdx.x;
  const int lane = tid & 63, wv = tid >> 6, q = lane >> 4, ln = lane & 15;
  const int row0 = blockIdx.x * 128;
  const int b = row0 >> 11;
  const bf16x8* __restrict__ Wp16 = (const bf16x8*)Wp;

  // epilogue constants: wave wv owns cols wv*64..+64
  float vv[4], dp[4];
  #pragma unroll
  for (int nt = 0; nt < 4; ++nt) {
    const int a = wv * 64 + nt * 16 + ln;
    vv[nt] = vvec[a];
    dp[nt] = decp[b * A_N + a];
  }

  // ---- stage: wave wv stages rows row0+wv*16..+16, full 2KB per row;
  // lane covers 8 consecutive floats (32B). 4-row batches cap registers.
  {
    const float* srow = enc + (size_t)(row0 + wv * 16) * E_N + lane * 8;
    #pragma unroll 1
    for (int b4 = 0; b4 < 4; ++b4) {
      f32x4 u[4], w4[4];
      #pragma unroll
      for (int j = 0; j < 4; ++j) {
        const int r = b4 * 4 + j;
        u[j]  = *(const f32x4*)(srow + (size_t)r * E_N);
        w4[j] = *(const f32x4*)(srow + (size_t)r * E_N + 4);
      }
      #pragma unroll
      for (int j = 0; j < 4; ++j) {
        uint4 o;
        o.x = f2bfu(u[j].x)  | (f2bfu(u[j].y)  << 16);
        o.y = f2bfu(u[j].z)  | (f2bfu(u[j].w)  << 16);
        o.z = f2bfu(w4[j].x) | (f2bfu(w4[j].y) << 16);
        o.w = f2bfu(w4[j].z) | (f2bfu(w4[j].w) << 16);
        *(uint4*)(lds + a_off(wv * 16 + b4 * 4 + j, lane * 16)) = o;
      }
    }
  }
  __syncthreads();

  // ---- compute: 16 K-steps (K=32 each), zero barriers, unroll 2 so the
  // compiler can hoist step k+1's B-loads above step k's MFMAs.
  const bf16x8* __restrict__ wb = Wp16 + (size_t)(wv * 4) * 1024 + lane;
  f32x4 acc[8][4] = {};
  #pragma unroll 2
  for (int kss = 0; kss < 16; ++kss) {
    bf16x8 bfr[4];
    #pragma unroll
    for (int nt = 0; nt < 4; ++nt)
      bfr[nt] = wb[nt * 1024 + kss * 64];
    #pragma unroll
    for (int h = 0; h < 2; ++h) {
      bf16x8 afr[4];
      #pragma unroll
      for (int mt = 0; mt < 4; ++mt)
        afr[mt] = *(const bf16x8*)(
            lds + a_off((h * 4 + mt) * 16 + ln, kss * 64 + q * 16));
      #pragma unroll
      for (int mt = 0; mt < 4; ++mt)
        #pragma unroll
        for (int nt = 0; nt < 4; ++nt)
          acc[h * 4 + mt][nt] = __builtin_amdgcn_mfma_f32_16x16x32_bf16(
              afr[mt], bfr[nt], acc[h * 4 + mt][nt], 0, 0, 0);
    }
  }

  // ---- epilogue: tanh(x + decp) * v; per-wave partial over 64 cols ----
  float* red = (float*)(lds + RED_OFF);
  #pragma unroll
  for (int mt = 0; mt < 8; ++mt) {
    #pragma unroll
    for (int r = 0; r < 4; ++r) {
      float s = 0.f;
      #pragma unroll
      for (int nt = 0; nt < 4; ++nt) {
        float x = acc[mt][nt][r] + dp[nt];
        x = fminf(9.f, fmaxf(-9.f, x));
        const float ex = __expf(2.f * x);
        s = fmaf(__fdividef(ex - 1.f, ex + 1.f), vv[nt], s);
      }
      s += __shfl_xor(s, 1);
      s += __shfl_xor(s, 2);
      s += __shfl_xor(s, 4);
      s += __shfl_xor(s, 8);
      if (ln == 0) red[wv * 128 + mt * 16 + q * 4 + r] = s;
    }
  }
  __syncthreads();
  if (tid < 128) {
    float s = 0.f;
    #pragma unroll
    for (int w8 = 0; w8 < 8; ++w8) s += red[w8 * 128 + tid];
    scores[row0 + tid] = s;
  }
}

// ------- K2: softmax over S per b -------------------------------------------
__global__ __launch_bounds__(256) void k_softmax(const float* __restrict__ scores,
                                                 float* __restrict__ attn) {
  const int b = blockIdx.x, tid = threadIdx.x;
  float l[8];
  float mx = -3.4e38f;
  #pragma unroll
  for (int i = 0; i < 8; ++i) {
    l[i] = scores[b * S_N + i * 256 + tid];
    mx = fmaxf(mx, l[i]);
  }
  #pragma unroll
  for (int m = 1; m < 64; m <<= 1) mx = fmaxf(mx, __shfl_xor(mx, m));
  __shared__ float sred[8];
  if ((tid & 63) == 0) sred[tid >> 6] = mx;
  __syncthreads();
  mx = fmaxf(fmaxf(sred[0], sred[1]), fmaxf(sred[2], sred[3]));
  float se = 0.f;
  #pragma unroll
  for (int i = 0; i < 8; ++i) { l[i] = __expf(l[i] - mx); se += l[i]; }
  #pragma unroll
  for (int m = 1; m < 64; m <<= 1) se += __shfl_xor(se, m);
  if ((tid & 63) == 0) sred[4 + (tid >> 6)] = se;
  __syncthreads();
  se = sred[4] + sred[5] + sred[6] + sred[7];
  const float inv = 1.f / se;
  #pragma unroll
  for (int i = 0; i < 8; ++i) attn[b * S_N + i * 256 + tid] = l[i] * inv;
}

// ------- K3: context[b][e] = sum_s w[b][s] * enc[b][s][e] -------------------
__global__ __launch_bounds__(512) void k_context(const float* __restrict__ enc,
                                                 const float* __restrict__ attn,
                                                 float* __restrict__ ctx) {
  const int blk = blockIdx.x;
  const int b = blk >> 2, eq = blk & 3;
  const int tid = threadIdx.x;
  const int te = tid & 31, sg = tid >> 5;   // 16 s-groups of 128 rows
  const int e0 = eq * 128 + te * 4;
  const float* ep = enc + (size_t)b * S_N * E_N + e0;
  const float* wp = attn + b * S_N;
  f32x4 acc = {0.f, 0.f, 0.f, 0.f};
  const int s0 = sg * 128;
  #pragma unroll 4
  for (int s = s0; s < s0 + 128; ++s) {
    const float w = wp[s];
    const f32x4 ev = *(const f32x4*)(ep + (size_t)s * E_N);
    acc += w * ev;
  }
  __shared__ f32x4 red[16][32];
  red[sg][te] = acc;
  __syncthreads();
  if (sg == 0) {
    f32x4 t = red[0][te];
    #pragma unroll
    for (int g = 1; g < 16; ++g) t += red[g][te];
    *(f32x4*)(ctx + (size_t)b * E_N + e0) = t;
  }
}

// ------- launch -------------------------------------------------------------
extern "C" void kernel_launch(void* const* d_in, const int* in_sizes, int n_in,
                              void* d_out, int out_size, void* d_ws, size_t ws_size,
                              hipStream_t stream) {
  const float* enc = (const float*)d_in[0];
  const float* dh  = (const float*)d_in[1];
  const float* We  = (const float*)d_in[2];
  const float* Wd  = (const float*)d_in[3];
  const float* v   = (const float*)d_in[4];

  float* out_ctx  = (float*)d_out;
  float* out_attn = out_ctx + B_N * E_N;

  float* scores = (float*)d_ws;                       // 131072 f32
  float* decp   = scores + B_N * S_N;                 // 32768 f32
  unsigned short* Wp = (unsigned short*)(decp + B_N * A_N);  // 262144 bf16 packed

  k_pack   <<<128, 256, 0, stream>>>(We, Wp);
  k_decproj<<<B_N, 256, 0, stream>>>(dh, Wd, decp);
  k_scores <<<(B_N * S_N) / 128, 512, 0, stream>>>(enc, Wp, decp, v, scores);
  k_softmax<<<B_N, 256, 0, stream>>>(scores, out_attn);
  k_context<<<B_N * 4, 512, 0, stream>>>(enc, out_attn, out_ctx);
}